// Round 12
// baseline (170.055 us; speedup 1.0000x reference)
//
#include <hip/hip_runtime.h>
#include <hip/hip_fp16.h>
#include <stdint.h>

// ---------------------------------------------------------------------------
// 2D DCT-II (unnormalized, 4096x4096 fp32), FFT path, v13:
//   v12 (fp16 V+H, 153.9 us) with the column pass fused at 2-block/CU
//   occupancy (v11's fusion failed only because 128 KB LDS -> 1 block/CU):
//   1. dct_rows : x  -> ws  (V fp16, 32 MB; column-Makhoul folded into the
//                  output row index: row 2b -> b, row 2b+1 -> 4095-b)
//   2. col_dct2 : ws -> out (one block = 2 complex cols (4 real) x all 4096
//                  rows in 68 KB padded LDS; radix-16^3 Stockham over rows;
//                  Hermitian/expk epilogue; fp32 final Z). 512 thr, 2 blk/CU.
//   H intermediate GONE: array traffic 256 MB (v12) -> 192 MB.
//   LDS layout idx = 2n + c + (n>>3) (pad 1 float2 per 8 rows): stage reads
//   ~2-way, stage writes ~4-way bank groups (never limiting in v9/v11).
//   Chunked XCD swizzle so neighboring 8 B column strips merge in L2.
// ---------------------------------------------------------------------------

#define NF 4096

__device__ __forceinline__ int physi(int e) { return e ^ ((e >> 4) & 15); }

// col_dct2 LDS index: 2 complex columns, padded every 8 rows.
__device__ __forceinline__ int cfi2(int n, int c) {
    return 2 * n + c + (n >> 3);
}

__device__ __forceinline__ float2 cadd(float2 a, float2 b) {
    float2 r; r.x = a.x + b.x; r.y = a.y + b.y; return r;
}
__device__ __forceinline__ float2 csub(float2 a, float2 b) {
    float2 r; r.x = a.x - b.x; r.y = a.y - b.y; return r;
}
__device__ __forceinline__ float2 cmulc(float2 a, float2 b) {
    float2 r; r.x = a.x * b.x - a.y * b.y; r.y = a.x * b.y + a.y * b.x; return r;
}
__device__ __forceinline__ float2 rotm(float2 a) {  // -i * a
    float2 r; r.x = a.y; r.y = -a.x; return r;
}

// tw layout (float2 units):
//   [0,64)      radix-8 Ls=8 table (legacy slot, unused in v13)
//   [64,320)    radix-16 stage-1    w[p][u] = exp(-2pi*i*p*u/256)  p,u<16
//   [320,4416)  radix-16 stage-2    w[p][u] = exp(-2pi*i*p*u/4096) p<256,u<16
// ek: expk[k] = (cos(pi*k/8192), sin(pi*k/8192)), 4096 entries.
__global__ __launch_bounds__(256) void setup_tables(float* __restrict__ tw,
                                                    float* __restrict__ ek) {
    int idx = blockIdx.x * 256 + threadIdx.x;
    if (idx < 4416) {
        int p, u; float denom;
        if (idx < 64)       { p = idx >> 3;         u = idx & 7;  denom = 64.0f; }
        else if (idx < 320) { int r = idx - 64;  p = r >> 4; u = r & 15; denom = 256.0f; }
        else                { int r = idx - 320; p = r >> 4; u = r & 15; denom = 4096.0f; }
        float phi = (float)(p * u) * (6.283185307179586f / denom);
        float s, c; __sincosf(phi, &s, &c);
        tw[2 * idx]     = c;
        tw[2 * idx + 1] = -s;
    } else if (idx < 8512) {
        int k = idx - 4416;
        float th = (float)k * (3.141592653589793f / 8192.0f);
        float s, c; __sincosf(th, &s, &c);
        ek[2 * k]     = c;
        ek[2 * k + 1] = s;
    }
}

#define RADIX8(Xv, E0, E1, E2, E3, O0, g1, g2, g3)                             \
    float2 t0 = cadd(Xv[0], Xv[4]), t1 = csub(Xv[0], Xv[4]);                   \
    float2 t2 = cadd(Xv[2], Xv[6]), t3 = csub(Xv[2], Xv[6]);                   \
    float2 E0 = cadd(t0, t2), E2 = csub(t0, t2);                               \
    float2 r3 = rotm(t3);                                                      \
    float2 E1 = cadd(t1, r3), E3 = csub(t1, r3);                               \
    float2 s0 = cadd(Xv[1], Xv[5]), s1 = csub(Xv[1], Xv[5]);                   \
    float2 s2 = cadd(Xv[3], Xv[7]), s3 = csub(Xv[3], Xv[7]);                   \
    float2 O0 = cadd(s0, s2), O2 = csub(s0, s2);                               \
    float2 r7 = rotm(s3);                                                      \
    float2 O1 = cadd(s1, r7), O3 = csub(s1, r7);                               \
    const float SQ = 0.7071067811865476f;                                      \
    float2 g1; g1.x = SQ * (O1.x + O1.y); g1.y = SQ * (O1.y - O1.x);           \
    float2 g2 = rotm(O2);                                                      \
    float2 g3; g3.x = SQ * (O3.y - O3.x); g3.y = -SQ * (O3.x + O3.y);

// Full radix-8 butterfly to out[8] (self-scoped, reusable in one scope).
#define RADIX8_OUT(Xv, Ov)                                                     \
    {                                                                          \
        RADIX8(Xv, E0, E1, E2, E3, O0, g1, g2, g3)                             \
        Ov[0] = cadd(E0, O0); Ov[1] = cadd(E1, g1);                            \
        Ov[2] = cadd(E2, g2); Ov[3] = cadd(E3, g3);                            \
        Ov[4] = csub(E0, O0); Ov[5] = csub(E1, g1);                            \
        Ov[6] = csub(E2, g2); Ov[7] = csub(E3, g3);                            \
    }

// In-place 16-pt DFT: X[i] = E[i&7] +/- W16^i * O[i&7], E/O = DFT8(even/odd).
__device__ __forceinline__ void dft16(float2* x) {
    float2 E[8], O[8];
    {
        float2 a[8];
        #pragma unroll
        for (int m = 0; m < 8; ++m) a[m] = x[2 * m];
        RADIX8_OUT(a, E)
    }
    {
        float2 a[8];
        #pragma unroll
        for (int m = 0; m < 8; ++m) a[m] = x[2 * m + 1];
        RADIX8_OUT(a, O)
    }
    const float2 W1 = { 0.9238795325112867f, -0.3826834323650898f};
    const float2 W2 = { 0.7071067811865476f, -0.7071067811865476f};
    const float2 W3 = { 0.3826834323650898f, -0.9238795325112867f};
    const float2 W5 = {-0.3826834323650898f, -0.9238795325112867f};
    const float2 W6 = {-0.7071067811865476f, -0.7071067811865476f};
    const float2 W7 = {-0.9238795325112867f, -0.3826834323650898f};
    float2 t;
    x[0] = cadd(E[0], O[0]);  x[8]  = csub(E[0], O[0]);
    t = cmulc(O[1], W1); x[1] = cadd(E[1], t); x[9]  = csub(E[1], t);
    t = cmulc(O[2], W2); x[2] = cadd(E[2], t); x[10] = csub(E[2], t);
    t = cmulc(O[3], W3); x[3] = cadd(E[3], t); x[11] = csub(E[3], t);
    t = rotm(O[4]);      x[4] = cadd(E[4], t); x[12] = csub(E[4], t);
    t = cmulc(O[5], W5); x[5] = cadd(E[5], t); x[13] = csub(E[5], t);
    t = cmulc(O[6], W6); x[6] = cadd(E[6], t); x[14] = csub(E[6], t);
    t = cmulc(O[7], W7); x[7] = cadd(E[7], t); x[15] = csub(E[7], t);
}

// One workgroup (256 thr) = TWO input rows (2b, 2b+1), pair-packed (v7b,
// verified). Dense float4 loads, Makhoul scatter to LDS, radix-16 Stockham
// (Ls = 1, 16, 256), Hermitian/expk epilogue -> FP16 stores.
// Output rows written PERMUTED for the column-Makhoul: 2b -> b, 2b+1 -> 4095-b.
__global__ __launch_bounds__(256) void dct_rows(const float* __restrict__ In,
                                                __half* __restrict__ Out,
                                                const float* __restrict__ tw,
                                                const float* __restrict__ ek) {
    __shared__ float2 buf[NF];   // 32 KB
    const int j = threadIdx.x;   // 0..255
    const int b = blockIdx.x;    // 0..2047
    const float* in0 = In + (size_t)(2 * b) * NF;
    const float* in1 = in0 + NF;
    __half* out0 = Out + (size_t)b * NF;            // sigma^-1(2b)   = b
    __half* out1 = Out + (size_t)(4095 - b) * NF;   // sigma^-1(2b+1) = 4095-b

    // ---- gather: dense float4 loads, Makhoul scatter into LDS
    const float4* i40 = (const float4*)in0;
    const float4* i41 = (const float4*)in1;
    #pragma unroll
    for (int c = 0; c < 4; ++c) {
        float4 a0 = i40[j + 256 * c];
        float4 a1 = i41[j + 256 * c];
        int nb = 2 * j + 512 * c;              // = 2*ch, ch = j+256c
        float2 z0; z0.x = a0.x; z0.y = a1.x;   // even -> n = nb
        float2 z1; z1.x = a0.z; z1.y = a1.z;   // even -> n = nb+1
        float2 z2; z2.x = a0.y; z2.y = a1.y;   // odd  -> 4095-nb
        float2 z3; z3.x = a0.w; z3.y = a1.w;   // odd  -> 4094-nb
        buf[physi(nb)]        = z0;
        buf[physi(nb + 1)]    = z1;
        buf[physi(4095 - nb)] = z2;
        buf[physi(4094 - nb)] = z3;
    }
    __syncthreads();

    float2 x[16];

    // ---- stage 0 (Ls=1): read j+256k from LDS, DFT16, write 16j+i
    #pragma unroll
    for (int k = 0; k < 16; ++k)
        x[k] = buf[physi(j + 256 * k)];
    dft16(x);
    __syncthreads();
    #pragma unroll
    for (int i = 0; i < 16; ++i)
        buf[physi(16 * j + i)] = x[i];
    __syncthreads();

    // ---- stage 1 (Ls=16): read j+256k, twiddle, DFT16, write p+256q+16i
    {
        const int p = j & 15, q = j >> 4;
        #pragma unroll
        for (int k = 0; k < 16; ++k)
            x[k] = buf[physi(j + 256 * k)];
        const float2* twp = (const float2*)tw + 64 + p * 16;
        #pragma unroll
        for (int k = 1; k < 16; ++k)
            x[k] = cmulc(x[k], twp[k]);
        dft16(x);
        __syncthreads();
        int wb = p + 256 * q;
        #pragma unroll
        for (int i = 0; i < 16; ++i)
            buf[physi(wb + 16 * i)] = x[i];
        __syncthreads();
    }

    // ---- stage 2 (Ls=256, p=j): read/write own slots j+256i, no mid barrier
    {
        #pragma unroll
        for (int k = 0; k < 16; ++k)
            x[k] = buf[physi(j + 256 * k)];
        const float2* twp = (const float2*)tw + 320 + j * 16;
        #pragma unroll
        for (int k = 1; k < 16; ++k)
            x[k] = cmulc(x[k], twp[k]);
        dft16(x);
        #pragma unroll
        for (int i = 0; i < 16; ++i)
            buf[physi(j + 256 * i)] = x[i];   // own slots only
    }
    __syncthreads();

    // ---- epilogue: Zk from regs; partner Zm via LDS; fp16 stores
    #pragma unroll
    for (int i = 0; i < 16; ++i) {
        int k = j + 256 * i;
        int m = (NF - k) & (NF - 1);
        float2 Zk = x[i];
        float2 Zm = buf[physi(m)];
        float2 E = ((const float2*)ek)[k];
        out0[k] = __float2half(0.5f * ((Zk.x + Zm.x) * E.x + (Zk.y - Zm.y) * E.y));
        out1[k] = __float2half(0.5f * ((Zk.y + Zm.y) * E.x - (Zk.x - Zm.x) * E.y));
    }
}

// ---------------------------------------------------------------------------
// Fused column pass, 2-block/CU variant: one block = 2 complex columns
// (real cols [4ct, 4ct+4)) x all 4096 rows in 68 KB padded LDS. 512 thr:
// c = t&1 (complex column), j = t>>1 (butterfly job 0..255). Gather reads
// one uint2 (4 halfs = both columns) per row; 3 radix-16 stages; Hermitian/
// expk epilogue; fp32 float2 stores. V rows already column-Makhoul-permuted.
// ---------------------------------------------------------------------------
__global__ __launch_bounds__(512) void col_dct2(const __half* __restrict__ V,
                                                float* __restrict__ Out,
                                                const float* __restrict__ tw,
                                                const float* __restrict__ ek) {
    extern __shared__ float2 buf[];   // 8704 float2 = 68 KB (padded)
    const int t = threadIdx.x;
    // chunked XCD swizzle: each XCD gets 128 consecutive column groups.
    const int bi = blockIdx.x;                  // 0..1023
    const int ct = (bi & 7) * 128 + (bi >> 3);  // bijective (1024 = 8*128)
    const int c = t & 1;                        // complex column 0..1
    const int j = t >> 1;                       // butterfly job 0..255

    // ---- gather: thread t loads rows t+512k, both columns in one uint2
    #pragma unroll
    for (int k = 0; k < 8; ++k) {
        int r = t + 512 * k;
        uint2 v = *(const uint2*)(V + (size_t)r * NF + 4 * ct);
        buf[cfi2(r, 0)] = __half22float2(*(__half2*)&v.x);
        buf[cfi2(r, 1)] = __half22float2(*(__half2*)&v.y);
    }
    __syncthreads();

    float2 x[16];

    // ---- stage 0 (Ls=1): read j+256k, DFT16, write 16j+i
    #pragma unroll
    for (int k = 0; k < 16; ++k)
        x[k] = buf[cfi2(j + 256 * k, c)];
    dft16(x);
    __syncthreads();
    #pragma unroll
    for (int i = 0; i < 16; ++i)
        buf[cfi2(16 * j + i, c)] = x[i];
    __syncthreads();

    // ---- stage 1 (Ls=16): read j+256k, twiddle, DFT16, write p+256q+16i
    {
        const int p = j & 15, q = j >> 4;
        #pragma unroll
        for (int k = 0; k < 16; ++k)
            x[k] = buf[cfi2(j + 256 * k, c)];
        const float2* twp = (const float2*)tw + 64 + p * 16;
        #pragma unroll
        for (int k = 1; k < 16; ++k)
            x[k] = cmulc(x[k], twp[k]);
        dft16(x);
        __syncthreads();
        int wb = p + 256 * q;
        #pragma unroll
        for (int i = 0; i < 16; ++i)
            buf[cfi2(wb + 16 * i, c)] = x[i];
        __syncthreads();
    }

    // ---- stage 2 (Ls=256, p=j): read/write own slots j+256i
    {
        #pragma unroll
        for (int k = 0; k < 16; ++k)
            x[k] = buf[cfi2(j + 256 * k, c)];
        const float2* twp = (const float2*)tw + 320 + j * 16;
        #pragma unroll
        for (int k = 1; k < 16; ++k)
            x[k] = cmulc(x[k], twp[k]);
        dft16(x);
        #pragma unroll
        for (int i = 0; i < 16; ++i)
            buf[cfi2(j + 256 * i, c)] = x[i];   // own slots only
    }
    __syncthreads();

    // ---- epilogue: Zk from regs, partner Zm via LDS; fp32 float2 stores
    float* base = Out + 4 * (size_t)ct;
    #pragma unroll
    for (int i = 0; i < 16; ++i) {
        int k = j + 256 * i;
        int m = (NF - k) & (NF - 1);
        float2 Zk = x[i];
        float2 Zm = buf[cfi2(m, c)];
        float2 E = ((const float2*)ek)[k];
        float2 r;
        r.x = 0.5f * ((Zk.x + Zm.x) * E.x + (Zk.y - Zm.y) * E.y);
        r.y = 0.5f * ((Zk.y + Zm.y) * E.x - (Zk.x - Zm.x) * E.y);
        *(float2*)&base[(size_t)k * NF + 2 * c] = r;
    }
}

extern "C" void kernel_launch(void* const* d_in, const int* in_sizes, int n_in,
                              void* d_out, int out_size, void* d_ws, size_t ws_size,
                              hipStream_t stream) {
    const float* x = (const float*)d_in[0];
    float* out = (float*)d_out;

    float* tw = (float*)d_ws;           // 4416 float2 = 8832 floats
    float* ek = tw + 8832;              // 4096 float2 = 8192 floats
    __half* V = (__half*)(ek + 8192);   // 4096*4096 halfs (32 MB)
    if (ws_size < (size_t)68096 + (size_t)NF * NF * sizeof(__half)) return;

    static bool attr_done = false;
    if (!attr_done) {
        (void)hipFuncSetAttribute((const void*)col_dct2,
                                  hipFuncAttributeMaxDynamicSharedMemorySize,
                                  69632);
        attr_done = true;
    }

    setup_tables<<<34, 256, 0, stream>>>(tw, ek);
    dct_rows<<<NF / 2, 256, 0, stream>>>(x, V, tw, ek);       // ws = V (fp16)
    col_dct2<<<1024, 512, 69632, stream>>>(V, out, tw, ek);   // out = Z (fp32)
}

// Round 13
// 158.745 us; speedup vs baseline: 1.0712x; 1.0712x over previous
//
#include <hip/hip_runtime.h>
#include <hip/hip_fp16.h>
#include <stdint.h>

// ---------------------------------------------------------------------------
// 2D DCT-II (unnormalized, 4096x4096 fp32), FFT path, v14:
//   v12 dct_rows (verified) + fused column pass satisfying BOTH failed-fusion
//   constraints: 32 B write strips (v13's 16 B strips write-amplified 64->95
//   MB) and 2 blocks/CU (v11's 128 KB LDS was 1 blk/CU latency-serial).
//   Trick: LDS holds the column data as fp16 __half2 complexes -> 4 complex
//   columns x 4096 rows = ~66 KB -> 2 blocks/CU, 1024 threads (32 waves/CU).
//   1. dct_rows : x  -> ws  (V fp16, 32 MB; column-Makhoul folded into the
//                  output row index: row 2b -> b, row 2b+1 -> 4095-b)
//   2. col_dct3 : ws -> out (one block = 4 complex cols (8 real) x all 4096
//                  rows, fp16 LDS; radix-16^3 Stockham over rows, arithmetic
//                  in fp32, LDS round-trips in fp16; Hermitian/expk epilogue;
//                  fp32 final Z, 32 B/row/block contiguous stores).
//   H intermediate GONE: array traffic 256 MB (v12) -> 192 MB.
//   LDS index cfi3(n,c) = 4n + c + (n>>3) (half2 units): stage writes
//   conflict-free (bank = (66j+..) mod 32 distinct over j), reads 2-way.
//   Added fp16-LDS rounding error ~ +-10 absolute (absmax 64, thr 231.7).
// ---------------------------------------------------------------------------

#define NF 4096

__device__ __forceinline__ int physi(int e) { return e ^ ((e >> 4) & 15); }

// col_dct3 LDS index (__half2 units): 4 complex columns, pad 1 per 8 rows.
__device__ __forceinline__ int cfi3(int n, int c) {
    return 4 * n + c + (n >> 3);
}

__device__ __forceinline__ float2 cadd(float2 a, float2 b) {
    float2 r; r.x = a.x + b.x; r.y = a.y + b.y; return r;
}
__device__ __forceinline__ float2 csub(float2 a, float2 b) {
    float2 r; r.x = a.x - b.x; r.y = a.y - b.y; return r;
}
__device__ __forceinline__ float2 cmulc(float2 a, float2 b) {
    float2 r; r.x = a.x * b.x - a.y * b.y; r.y = a.x * b.y + a.y * b.x; return r;
}
__device__ __forceinline__ float2 rotm(float2 a) {  // -i * a
    float2 r; r.x = a.y; r.y = -a.x; return r;
}

// tw layout (float2 units):
//   [0,64)      radix-8 Ls=8 table (legacy slot, unused in v14)
//   [64,320)    radix-16 stage-1    w[p][u] = exp(-2pi*i*p*u/256)  p,u<16
//   [320,4416)  radix-16 stage-2    w[p][u] = exp(-2pi*i*p*u/4096) p<256,u<16
// ek: expk[k] = (cos(pi*k/8192), sin(pi*k/8192)), 4096 entries.
__global__ __launch_bounds__(256) void setup_tables(float* __restrict__ tw,
                                                    float* __restrict__ ek) {
    int idx = blockIdx.x * 256 + threadIdx.x;
    if (idx < 4416) {
        int p, u; float denom;
        if (idx < 64)       { p = idx >> 3;         u = idx & 7;  denom = 64.0f; }
        else if (idx < 320) { int r = idx - 64;  p = r >> 4; u = r & 15; denom = 256.0f; }
        else                { int r = idx - 320; p = r >> 4; u = r & 15; denom = 4096.0f; }
        float phi = (float)(p * u) * (6.283185307179586f / denom);
        float s, c; __sincosf(phi, &s, &c);
        tw[2 * idx]     = c;
        tw[2 * idx + 1] = -s;
    } else if (idx < 8512) {
        int k = idx - 4416;
        float th = (float)k * (3.141592653589793f / 8192.0f);
        float s, c; __sincosf(th, &s, &c);
        ek[2 * k]     = c;
        ek[2 * k + 1] = s;
    }
}

#define RADIX8(Xv, E0, E1, E2, E3, O0, g1, g2, g3)                             \
    float2 t0 = cadd(Xv[0], Xv[4]), t1 = csub(Xv[0], Xv[4]);                   \
    float2 t2 = cadd(Xv[2], Xv[6]), t3 = csub(Xv[2], Xv[6]);                   \
    float2 E0 = cadd(t0, t2), E2 = csub(t0, t2);                               \
    float2 r3 = rotm(t3);                                                      \
    float2 E1 = cadd(t1, r3), E3 = csub(t1, r3);                               \
    float2 s0 = cadd(Xv[1], Xv[5]), s1 = csub(Xv[1], Xv[5]);                   \
    float2 s2 = cadd(Xv[3], Xv[7]), s3 = csub(Xv[3], Xv[7]);                   \
    float2 O0 = cadd(s0, s2), O2 = csub(s0, s2);                               \
    float2 r7 = rotm(s3);                                                      \
    float2 O1 = cadd(s1, r7), O3 = csub(s1, r7);                               \
    const float SQ = 0.7071067811865476f;                                      \
    float2 g1; g1.x = SQ * (O1.x + O1.y); g1.y = SQ * (O1.y - O1.x);           \
    float2 g2 = rotm(O2);                                                      \
    float2 g3; g3.x = SQ * (O3.y - O3.x); g3.y = -SQ * (O3.x + O3.y);

// Full radix-8 butterfly to out[8] (self-scoped, reusable in one scope).
#define RADIX8_OUT(Xv, Ov)                                                     \
    {                                                                          \
        RADIX8(Xv, E0, E1, E2, E3, O0, g1, g2, g3)                             \
        Ov[0] = cadd(E0, O0); Ov[1] = cadd(E1, g1);                            \
        Ov[2] = cadd(E2, g2); Ov[3] = cadd(E3, g3);                            \
        Ov[4] = csub(E0, O0); Ov[5] = csub(E1, g1);                            \
        Ov[6] = csub(E2, g2); Ov[7] = csub(E3, g3);                            \
    }

// In-place 16-pt DFT: X[i] = E[i&7] +/- W16^i * O[i&7], E/O = DFT8(even/odd).
__device__ __forceinline__ void dft16(float2* x) {
    float2 E[8], O[8];
    {
        float2 a[8];
        #pragma unroll
        for (int m = 0; m < 8; ++m) a[m] = x[2 * m];
        RADIX8_OUT(a, E)
    }
    {
        float2 a[8];
        #pragma unroll
        for (int m = 0; m < 8; ++m) a[m] = x[2 * m + 1];
        RADIX8_OUT(a, O)
    }
    const float2 W1 = { 0.9238795325112867f, -0.3826834323650898f};
    const float2 W2 = { 0.7071067811865476f, -0.7071067811865476f};
    const float2 W3 = { 0.3826834323650898f, -0.9238795325112867f};
    const float2 W5 = {-0.3826834323650898f, -0.9238795325112867f};
    const float2 W6 = {-0.7071067811865476f, -0.7071067811865476f};
    const float2 W7 = {-0.9238795325112867f, -0.3826834323650898f};
    float2 t;
    x[0] = cadd(E[0], O[0]);  x[8]  = csub(E[0], O[0]);
    t = cmulc(O[1], W1); x[1] = cadd(E[1], t); x[9]  = csub(E[1], t);
    t = cmulc(O[2], W2); x[2] = cadd(E[2], t); x[10] = csub(E[2], t);
    t = cmulc(O[3], W3); x[3] = cadd(E[3], t); x[11] = csub(E[3], t);
    t = rotm(O[4]);      x[4] = cadd(E[4], t); x[12] = csub(E[4], t);
    t = cmulc(O[5], W5); x[5] = cadd(E[5], t); x[13] = csub(E[5], t);
    t = cmulc(O[6], W6); x[6] = cadd(E[6], t); x[14] = csub(E[6], t);
    t = cmulc(O[7], W7); x[7] = cadd(E[7], t); x[15] = csub(E[7], t);
}

// One workgroup (256 thr) = TWO input rows (2b, 2b+1), pair-packed (v7b,
// verified). Dense float4 loads, Makhoul scatter to LDS, radix-16 Stockham
// (Ls = 1, 16, 256), Hermitian/expk epilogue -> FP16 stores.
// Output rows written PERMUTED for the column-Makhoul: 2b -> b, 2b+1 -> 4095-b.
__global__ __launch_bounds__(256) void dct_rows(const float* __restrict__ In,
                                                __half* __restrict__ Out,
                                                const float* __restrict__ tw,
                                                const float* __restrict__ ek) {
    __shared__ float2 buf[NF];   // 32 KB
    const int j = threadIdx.x;   // 0..255
    const int b = blockIdx.x;    // 0..2047
    const float* in0 = In + (size_t)(2 * b) * NF;
    const float* in1 = in0 + NF;
    __half* out0 = Out + (size_t)b * NF;            // sigma^-1(2b)   = b
    __half* out1 = Out + (size_t)(4095 - b) * NF;   // sigma^-1(2b+1) = 4095-b

    // ---- gather: dense float4 loads, Makhoul scatter into LDS
    const float4* i40 = (const float4*)in0;
    const float4* i41 = (const float4*)in1;
    #pragma unroll
    for (int c = 0; c < 4; ++c) {
        float4 a0 = i40[j + 256 * c];
        float4 a1 = i41[j + 256 * c];
        int nb = 2 * j + 512 * c;              // = 2*ch, ch = j+256c
        float2 z0; z0.x = a0.x; z0.y = a1.x;   // even -> n = nb
        float2 z1; z1.x = a0.z; z1.y = a1.z;   // even -> n = nb+1
        float2 z2; z2.x = a0.y; z2.y = a1.y;   // odd  -> 4095-nb
        float2 z3; z3.x = a0.w; z3.y = a1.w;   // odd  -> 4094-nb
        buf[physi(nb)]        = z0;
        buf[physi(nb + 1)]    = z1;
        buf[physi(4095 - nb)] = z2;
        buf[physi(4094 - nb)] = z3;
    }
    __syncthreads();

    float2 x[16];

    // ---- stage 0 (Ls=1): read j+256k from LDS, DFT16, write 16j+i
    #pragma unroll
    for (int k = 0; k < 16; ++k)
        x[k] = buf[physi(j + 256 * k)];
    dft16(x);
    __syncthreads();
    #pragma unroll
    for (int i = 0; i < 16; ++i)
        buf[physi(16 * j + i)] = x[i];
    __syncthreads();

    // ---- stage 1 (Ls=16): read j+256k, twiddle, DFT16, write p+256q+16i
    {
        const int p = j & 15, q = j >> 4;
        #pragma unroll
        for (int k = 0; k < 16; ++k)
            x[k] = buf[physi(j + 256 * k)];
        const float2* twp = (const float2*)tw + 64 + p * 16;
        #pragma unroll
        for (int k = 1; k < 16; ++k)
            x[k] = cmulc(x[k], twp[k]);
        dft16(x);
        __syncthreads();
        int wb = p + 256 * q;
        #pragma unroll
        for (int i = 0; i < 16; ++i)
            buf[physi(wb + 16 * i)] = x[i];
        __syncthreads();
    }

    // ---- stage 2 (Ls=256, p=j): read/write own slots j+256i, no mid barrier
    {
        #pragma unroll
        for (int k = 0; k < 16; ++k)
            x[k] = buf[physi(j + 256 * k)];
        const float2* twp = (const float2*)tw + 320 + j * 16;
        #pragma unroll
        for (int k = 1; k < 16; ++k)
            x[k] = cmulc(x[k], twp[k]);
        dft16(x);
        #pragma unroll
        for (int i = 0; i < 16; ++i)
            buf[physi(j + 256 * i)] = x[i];   // own slots only
    }
    __syncthreads();

    // ---- epilogue: Zk from regs; partner Zm via LDS; fp16 stores
    #pragma unroll
    for (int i = 0; i < 16; ++i) {
        int k = j + 256 * i;
        int m = (NF - k) & (NF - 1);
        float2 Zk = x[i];
        float2 Zm = buf[physi(m)];
        float2 E = ((const float2*)ek)[k];
        out0[k] = __float2half(0.5f * ((Zk.x + Zm.x) * E.x + (Zk.y - Zm.y) * E.y));
        out1[k] = __float2half(0.5f * ((Zk.y + Zm.y) * E.x - (Zk.x - Zm.x) * E.y));
    }
}

// ---------------------------------------------------------------------------
// Fused column pass v3: one block = 4 complex columns (real cols [8ct,8ct+8))
// x all 4096 rows in ~66 KB fp16 LDS (__half2 per complex). 1024 threads:
// c = t&3 (complex column), j = t>>2 (butterfly job 0..255). Arithmetic in
// fp32; LDS round-trips in fp16. 3 radix-16 stages; Hermitian/expk epilogue;
// fp32 stores, 32 B/row/block (no write amplification). 2 blocks/CU.
// V rows already column-Makhoul-permuted by dct_rows.
// ---------------------------------------------------------------------------
__global__ __launch_bounds__(1024) void col_dct3(const __half* __restrict__ V,
                                                 float* __restrict__ Out,
                                                 const float* __restrict__ tw,
                                                 const float* __restrict__ ek) {
    extern __shared__ __half2 buf[];   // cfi3 max 16898 half2 = ~66 KB
    const int t = threadIdx.x;
    // chunked XCD swizzle: each XCD gets 64 consecutive column groups.
    const int bi = blockIdx.x;                 // 0..511
    const int ct = (bi & 7) * 64 + (bi >> 3);  // bijective (512 = 8*64)
    const int c = t & 3;                       // complex column 0..3
    const int j = t >> 2;                      // butterfly job 0..255

    // ---- gather: thread t loads rows t+1024k (uint4 = 8 halfs = 4 complex)
    #pragma unroll
    for (int k = 0; k < 4; ++k) {
        int r = t + 1024 * k;
        uint4 v = *(const uint4*)(V + (size_t)r * NF + 8 * ct);
        buf[cfi3(r, 0)] = *(__half2*)&v.x;
        buf[cfi3(r, 1)] = *(__half2*)&v.y;
        buf[cfi3(r, 2)] = *(__half2*)&v.z;
        buf[cfi3(r, 3)] = *(__half2*)&v.w;
    }
    __syncthreads();

    float2 x[16];

    // ---- stage 0 (Ls=1): read j+256k, DFT16, write 16j+i
    #pragma unroll
    for (int k = 0; k < 16; ++k)
        x[k] = __half22float2(buf[cfi3(j + 256 * k, c)]);
    dft16(x);
    __syncthreads();
    #pragma unroll
    for (int i = 0; i < 16; ++i)
        buf[cfi3(16 * j + i, c)] = __floats2half2_rn(x[i].x, x[i].y);
    __syncthreads();

    // ---- stage 1 (Ls=16): read j+256k, twiddle, DFT16, write p+256q+16i
    {
        const int p = j & 15, q = j >> 4;
        #pragma unroll
        for (int k = 0; k < 16; ++k)
            x[k] = __half22float2(buf[cfi3(j + 256 * k, c)]);
        const float2* twp = (const float2*)tw + 64 + p * 16;
        #pragma unroll
        for (int k = 1; k < 16; ++k)
            x[k] = cmulc(x[k], twp[k]);
        dft16(x);
        __syncthreads();
        int wb = p + 256 * q;
        #pragma unroll
        for (int i = 0; i < 16; ++i)
            buf[cfi3(wb + 16 * i, c)] = __floats2half2_rn(x[i].x, x[i].y);
        __syncthreads();
    }

    // ---- stage 2 (Ls=256, p=j): read/write own slots j+256i
    {
        #pragma unroll
        for (int k = 0; k < 16; ++k)
            x[k] = __half22float2(buf[cfi3(j + 256 * k, c)]);
        const float2* twp = (const float2*)tw + 320 + j * 16;
        #pragma unroll
        for (int k = 1; k < 16; ++k)
            x[k] = cmulc(x[k], twp[k]);
        dft16(x);
        #pragma unroll
        for (int i = 0; i < 16; ++i)
            buf[cfi3(j + 256 * i, c)] = __floats2half2_rn(x[i].x, x[i].y);
    }
    __syncthreads();

    // ---- epilogue: Zk from regs (fp32), partner Zm via fp16 LDS;
    //      fp32 float2 stores, 4 lanes/row -> 32 B contiguous per row
    float* base = Out + 8 * (size_t)ct;
    #pragma unroll
    for (int i = 0; i < 16; ++i) {
        int k = j + 256 * i;
        int m = (NF - k) & (NF - 1);
        float2 Zk = x[i];
        float2 Zm = __half22float2(buf[cfi3(m, c)]);
        float2 E = ((const float2*)ek)[k];
        float2 r;
        r.x = 0.5f * ((Zk.x + Zm.x) * E.x + (Zk.y - Zm.y) * E.y);
        r.y = 0.5f * ((Zk.y + Zm.y) * E.x - (Zk.x - Zm.x) * E.y);
        *(float2*)&base[(size_t)k * NF + 2 * c] = r;
    }
}

extern "C" void kernel_launch(void* const* d_in, const int* in_sizes, int n_in,
                              void* d_out, int out_size, void* d_ws, size_t ws_size,
                              hipStream_t stream) {
    const float* x = (const float*)d_in[0];
    float* out = (float*)d_out;

    float* tw = (float*)d_ws;           // 4416 float2 = 8832 floats
    float* ek = tw + 8832;              // 4096 float2 = 8192 floats
    __half* V = (__half*)(ek + 8192);   // 4096*4096 halfs (32 MB)
    if (ws_size < (size_t)68096 + (size_t)NF * NF * sizeof(__half)) return;

    // cfi3 max index = 4*4095 + 3 + 511 = 16894 -> 16895 half2 = 67580 B
    static bool attr_done = false;
    if (!attr_done) {
        (void)hipFuncSetAttribute((const void*)col_dct3,
                                  hipFuncAttributeMaxDynamicSharedMemorySize,
                                  67584);
        attr_done = true;
    }

    setup_tables<<<34, 256, 0, stream>>>(tw, ek);
    dct_rows<<<NF / 2, 256, 0, stream>>>(x, V, tw, ek);       // ws = V (fp16)
    col_dct3<<<512, 1024, 67584, stream>>>(V, out, tw, ek);   // out = Z (fp32)
}

// Round 14
// 151.725 us; speedup vs baseline: 1.1208x; 1.0463x over previous
//
#include <hip/hip_runtime.h>
#include <hip/hip_fp16.h>
#include <stdint.h>

// ---------------------------------------------------------------------------
// 2D DCT-II (unnormalized, 4096x4096 fp32), FFT path, v15:
//   v12 3-kernel structure (best: 153.9 us) + FP16 LDS in all kernels.
//   Rationale: kernels pinned at ~2.3 TB/s vs fills' 6.6 because read/compute/
//   write phases only overlap across RESIDENT blocks, and 32 KB LDS capped
//   dct_rows at ~2.5 blocks/CU (31% occupancy). fp16 LDS halves footprint:
//   dct_rows 16 KB -> 8 blocks/CU possible; cf1/cf2 likewise. v14 proved the
//   fp16-LDS rounding is numerically free here (absmax stayed 64).
//   1. dct_rows : x  -> out (V fp16 in d_out's first 32 MB; column-Makhoul
//                  folded into output row index: 2b -> b, 2b+1 -> 4095-b)
//   2. col_fft1 : out -> B1 (per n1: 64-pt FFT over n2 + 4-step twiddle;
//                  H fp16 at row 64*k2+n1)
//   3. col_fft2 : B1 -> out (per k2-pair: 64-pt FFT over n1, Hermitian
//                  pairs block-local, expk epilogue, fp32 final Z)
//   Arithmetic fp32 in registers everywhere; only LDS storage is fp16.
// ---------------------------------------------------------------------------

#define NF 4096

__device__ __forceinline__ int physi(int e) { return e ^ ((e >> 4) & 15); }

__device__ __forceinline__ float2 cadd(float2 a, float2 b) {
    float2 r; r.x = a.x + b.x; r.y = a.y + b.y; return r;
}
__device__ __forceinline__ float2 csub(float2 a, float2 b) {
    float2 r; r.x = a.x - b.x; r.y = a.y - b.y; return r;
}
__device__ __forceinline__ float2 cmulc(float2 a, float2 b) {
    float2 r; r.x = a.x * b.x - a.y * b.y; r.y = a.x * b.y + a.y * b.x; return r;
}
__device__ __forceinline__ float2 rotm(float2 a) {  // -i * a
    float2 r; r.x = a.y; r.y = -a.x; return r;
}
__device__ __forceinline__ __half2 f2h(float2 a) {
    return __floats2half2_rn(a.x, a.y);
}
__device__ __forceinline__ float2 h2f(__half2 a) {
    return __half22float2(a);
}

// tw layout (float2 units):
//   [0,64)      radix-8 Ls=8 table  w[p][u] = exp(-2pi*i*p*u/64)   (col FFTs)
//   [64,320)    radix-16 stage-1    w[p][u] = exp(-2pi*i*p*u/256)  p,u<16
//   [320,4416)  radix-16 stage-2    w[p][u] = exp(-2pi*i*p*u/4096) p<256,u<16
// ek: expk[k] = (cos(pi*k/8192), sin(pi*k/8192)), 4096 entries.
__global__ __launch_bounds__(256) void setup_tables(float* __restrict__ tw,
                                                    float* __restrict__ ek) {
    int idx = blockIdx.x * 256 + threadIdx.x;
    if (idx < 4416) {
        int p, u; float denom;
        if (idx < 64)       { p = idx >> 3;         u = idx & 7;  denom = 64.0f; }
        else if (idx < 320) { int r = idx - 64;  p = r >> 4; u = r & 15; denom = 256.0f; }
        else                { int r = idx - 320; p = r >> 4; u = r & 15; denom = 4096.0f; }
        float phi = (float)(p * u) * (6.283185307179586f / denom);
        float s, c; __sincosf(phi, &s, &c);
        tw[2 * idx]     = c;
        tw[2 * idx + 1] = -s;
    } else if (idx < 8512) {
        int k = idx - 4416;
        float th = (float)k * (3.141592653589793f / 8192.0f);
        float s, c; __sincosf(th, &s, &c);
        ek[2 * k]     = c;
        ek[2 * k + 1] = s;
    }
}

#define RADIX8(Xv, E0, E1, E2, E3, O0, g1, g2, g3)                             \
    float2 t0 = cadd(Xv[0], Xv[4]), t1 = csub(Xv[0], Xv[4]);                   \
    float2 t2 = cadd(Xv[2], Xv[6]), t3 = csub(Xv[2], Xv[6]);                   \
    float2 E0 = cadd(t0, t2), E2 = csub(t0, t2);                               \
    float2 r3 = rotm(t3);                                                      \
    float2 E1 = cadd(t1, r3), E3 = csub(t1, r3);                               \
    float2 s0 = cadd(Xv[1], Xv[5]), s1 = csub(Xv[1], Xv[5]);                   \
    float2 s2 = cadd(Xv[3], Xv[7]), s3 = csub(Xv[3], Xv[7]);                   \
    float2 O0 = cadd(s0, s2), O2 = csub(s0, s2);                               \
    float2 r7 = rotm(s3);                                                      \
    float2 O1 = cadd(s1, r7), O3 = csub(s1, r7);                               \
    const float SQ = 0.7071067811865476f;                                      \
    float2 g1; g1.x = SQ * (O1.x + O1.y); g1.y = SQ * (O1.y - O1.x);           \
    float2 g2 = rotm(O2);                                                      \
    float2 g3; g3.x = SQ * (O3.y - O3.x); g3.y = -SQ * (O3.x + O3.y);

// Full radix-8 butterfly to out[8] (self-scoped, reusable in one scope).
#define RADIX8_OUT(Xv, Ov)                                                     \
    {                                                                          \
        RADIX8(Xv, E0, E1, E2, E3, O0, g1, g2, g3)                             \
        Ov[0] = cadd(E0, O0); Ov[1] = cadd(E1, g1);                            \
        Ov[2] = cadd(E2, g2); Ov[3] = cadd(E3, g3);                            \
        Ov[4] = csub(E0, O0); Ov[5] = csub(E1, g1);                            \
        Ov[6] = csub(E2, g2); Ov[7] = csub(E3, g3);                            \
    }

// In-place 16-pt DFT: X[i] = E[i&7] +/- W16^i * O[i&7], E/O = DFT8(even/odd).
__device__ __forceinline__ void dft16(float2* x) {
    float2 E[8], O[8];
    {
        float2 a[8];
        #pragma unroll
        for (int m = 0; m < 8; ++m) a[m] = x[2 * m];
        RADIX8_OUT(a, E)
    }
    {
        float2 a[8];
        #pragma unroll
        for (int m = 0; m < 8; ++m) a[m] = x[2 * m + 1];
        RADIX8_OUT(a, O)
    }
    const float2 W1 = { 0.9238795325112867f, -0.3826834323650898f};
    const float2 W2 = { 0.7071067811865476f, -0.7071067811865476f};
    const float2 W3 = { 0.3826834323650898f, -0.9238795325112867f};
    const float2 W5 = {-0.3826834323650898f, -0.9238795325112867f};
    const float2 W6 = {-0.7071067811865476f, -0.7071067811865476f};
    const float2 W7 = {-0.9238795325112867f, -0.3826834323650898f};
    float2 t;
    x[0] = cadd(E[0], O[0]);  x[8]  = csub(E[0], O[0]);
    t = cmulc(O[1], W1); x[1] = cadd(E[1], t); x[9]  = csub(E[1], t);
    t = cmulc(O[2], W2); x[2] = cadd(E[2], t); x[10] = csub(E[2], t);
    t = cmulc(O[3], W3); x[3] = cadd(E[3], t); x[11] = csub(E[3], t);
    t = rotm(O[4]);      x[4] = cadd(E[4], t); x[12] = csub(E[4], t);
    t = cmulc(O[5], W5); x[5] = cadd(E[5], t); x[13] = csub(E[5], t);
    t = cmulc(O[6], W6); x[6] = cadd(E[6], t); x[14] = csub(E[6], t);
    t = cmulc(O[7], W7); x[7] = cadd(E[7], t); x[15] = csub(E[7], t);
}

// One workgroup (256 thr) = TWO input rows (2b, 2b+1), pair-packed.
// v15: LDS buf is __half2 (16 KB -> up to 8 blocks/CU). Dense float4 loads,
// Makhoul scatter (fp32->fp16) to LDS, radix-16 Stockham (Ls = 1, 16, 256)
// with fp32 register arithmetic, Hermitian/expk epilogue -> FP16 stores.
// Output rows written PERMUTED for the column-Makhoul: 2b -> b, 2b+1 -> 4095-b.
__global__ __launch_bounds__(256) void dct_rows(const float* __restrict__ In,
                                                __half* __restrict__ Out,
                                                const float* __restrict__ tw,
                                                const float* __restrict__ ek) {
    __shared__ __half2 buf[NF];   // 16 KB
    const int j = threadIdx.x;   // 0..255
    const int b = blockIdx.x;    // 0..2047
    const float* in0 = In + (size_t)(2 * b) * NF;
    const float* in1 = in0 + NF;
    __half* out0 = Out + (size_t)b * NF;            // sigma^-1(2b)   = b
    __half* out1 = Out + (size_t)(4095 - b) * NF;   // sigma^-1(2b+1) = 4095-b

    // ---- gather: dense float4 loads, Makhoul scatter into LDS (fp16)
    const float4* i40 = (const float4*)in0;
    const float4* i41 = (const float4*)in1;
    #pragma unroll
    for (int c = 0; c < 4; ++c) {
        float4 a0 = i40[j + 256 * c];
        float4 a1 = i41[j + 256 * c];
        int nb = 2 * j + 512 * c;              // = 2*ch, ch = j+256c
        buf[physi(nb)]        = __floats2half2_rn(a0.x, a1.x);  // n = nb
        buf[physi(nb + 1)]    = __floats2half2_rn(a0.z, a1.z);  // n = nb+1
        buf[physi(4095 - nb)] = __floats2half2_rn(a0.y, a1.y);  // 4095-nb
        buf[physi(4094 - nb)] = __floats2half2_rn(a0.w, a1.w);  // 4094-nb
    }
    __syncthreads();

    float2 x[16];

    // ---- stage 0 (Ls=1): read j+256k from LDS, DFT16, write 16j+i
    #pragma unroll
    for (int k = 0; k < 16; ++k)
        x[k] = h2f(buf[physi(j + 256 * k)]);
    dft16(x);
    __syncthreads();
    #pragma unroll
    for (int i = 0; i < 16; ++i)
        buf[physi(16 * j + i)] = f2h(x[i]);
    __syncthreads();

    // ---- stage 1 (Ls=16): read j+256k, twiddle, DFT16, write p+256q+16i
    {
        const int p = j & 15, q = j >> 4;
        #pragma unroll
        for (int k = 0; k < 16; ++k)
            x[k] = h2f(buf[physi(j + 256 * k)]);
        const float2* twp = (const float2*)tw + 64 + p * 16;
        #pragma unroll
        for (int k = 1; k < 16; ++k)
            x[k] = cmulc(x[k], twp[k]);
        dft16(x);
        __syncthreads();
        int wb = p + 256 * q;
        #pragma unroll
        for (int i = 0; i < 16; ++i)
            buf[physi(wb + 16 * i)] = f2h(x[i]);
        __syncthreads();
    }

    // ---- stage 2 (Ls=256, p=j): read/write own slots j+256i, no mid barrier
    {
        #pragma unroll
        for (int k = 0; k < 16; ++k)
            x[k] = h2f(buf[physi(j + 256 * k)]);
        const float2* twp = (const float2*)tw + 320 + j * 16;
        #pragma unroll
        for (int k = 1; k < 16; ++k)
            x[k] = cmulc(x[k], twp[k]);
        dft16(x);
        #pragma unroll
        for (int i = 0; i < 16; ++i)
            buf[physi(j + 256 * i)] = f2h(x[i]);   // own slots only
    }
    __syncthreads();

    // ---- epilogue: Zk from regs (fp32); partner Zm via fp16 LDS; fp16 out
    #pragma unroll
    for (int i = 0; i < 16; ++i) {
        int k = j + 256 * i;
        int m = (NF - k) & (NF - 1);
        float2 Zk = x[i];
        float2 Zm = h2f(buf[physi(m)]);
        float2 E = ((const float2*)ek)[k];
        out0[k] = __float2half(0.5f * ((Zk.x + Zm.x) * E.x + (Zk.y - Zm.y) * E.y));
        out1[k] = __float2half(0.5f * ((Zk.y + Zm.y) * E.x - (Zk.x - Zm.x) * E.y));
    }
}

// ---------------------------------------------------------------------------
// Column pass, four-step step 1 (fp16 in/out, fp16 LDS = 16 KB): TWO
// column-pairs per thread. One block = one n1 residue (blockIdx.y) x one
// 128-real-column tile (blockIdx.x, 0..31). 256 threads: g = ct*32 + (t&31)
// handles complex pairs {2g, 2g+1}; j = t>>5 is the butterfly job.
// ---------------------------------------------------------------------------
__global__ __launch_bounds__(256) void col_fft1(const __half* __restrict__ V,
                                                __half* __restrict__ S,
                                                const float* __restrict__ tw) {
    __shared__ __half2 T[64][64];   // 16 KB: [row][complex col]
    __shared__ float2 w64[64];
    const int ct = blockIdx.x, n1 = blockIdx.y;
    const int t = threadIdx.x;
    const int cp4 = t & 31, j = t >> 5;
    const int g = ct * 32 + cp4;                     // 0..1023
    const uint2* in2 = (const uint2*)V + g;          // row stride 1024 uint2

    if (t < 64) {
        int m = (n1 * t) & 4095;
        float phi = (float)m * -1.5339807878856412e-3f;  // -2pi/4096
        float s, c; __sincosf(phi, &s, &c);
        float2 w; w.x = c; w.y = s;
        w64[t] = w;
    }

    float2 xA[8], xB[8];
    #pragma unroll
    for (int k = 0; k < 8; ++k) {
        uint2 v = in2[(size_t)(n1 + 64 * (j + 8 * k)) * 1024];
        xA[k] = h2f(*(__half2*)&v.x);   // complex 2g
        xB[k] = h2f(*(__half2*)&v.y);   // complex 2g+1
    }
    {   // stage A (Ls=1): outputs to LDS rows 8j+i, both complexes as uint2
        float2 rA[8], rB[8];
        RADIX8_OUT(xA, rA)
        RADIX8_OUT(xB, rB)
        #pragma unroll
        for (int i = 0; i < 8; ++i) {
            __half2 hA = f2h(rA[i]), hB = f2h(rB[i]);
            uint2 w; w.x = *(unsigned int*)&hA; w.y = *(unsigned int*)&hB;
            *(uint2*)&T[8 * j + i][2 * cp4] = w;
        }
    }
    __syncthreads();

    float2 oA[8], oB[8];
    {   // stage B (Ls=8): p=j, natural-order outputs k2 = j+8i
        #pragma unroll
        for (int k = 0; k < 8; ++k) {
            uint2 v = *(const uint2*)&T[j + 8 * k][2 * cp4];
            xA[k] = h2f(*(__half2*)&v.x);
            xB[k] = h2f(*(__half2*)&v.y);
        }
        const float2* twp = (const float2*)tw + j * 8;   // Ls=8 section
        #pragma unroll
        for (int k = 1; k < 8; ++k) {
            xA[k] = cmulc(xA[k], twp[k]);
            xB[k] = cmulc(xB[k], twp[k]);
        }
        RADIX8_OUT(xA, oA)
        RADIX8_OUT(xB, oB)
    }

    // four-step twiddle from LDS, store both pairs (fp16) to S row 64*k2+n1
    uint2* out2 = (uint2*)S + g;
    #pragma unroll
    for (int i = 0; i < 8; ++i) {
        int k2 = j + 8 * i;
        float2 hA = cmulc(oA[i], w64[k2]);
        float2 hB = cmulc(oB[i], w64[k2]);
        __half2 a2 = f2h(hA), b2 = f2h(hB);
        uint2 w; w.x = *(unsigned int*)&a2; w.y = *(unsigned int*)&b2;
        out2[(size_t)(64 * k2 + n1) * 1024] = w;
    }
}

// ---------------------------------------------------------------------------
// Column pass, four-step step 2 + Hermitian/expk epilogue (fp16 H input,
// fp16 LDS = 16 KB). One block = k2-pair {ga, gb} = {bp, 64-bp} (bp=0 ->
// {0,32}) x one 64-real-column tile. 512 thr: gi = t>>8, j = (t>>5)&7,
// cp = t&31.
// ---------------------------------------------------------------------------
__global__ __launch_bounds__(512) void col_fft2(const __half* __restrict__ S,
                                                float* __restrict__ Out,
                                                const float* __restrict__ tw,
                                                const float* __restrict__ ek) {
    __shared__ __half2 T[2][64][32];   // 16 KB
    const int ct = blockIdx.x, bp = blockIdx.y;
    const int ga = bp, gb = (bp == 0) ? 32 : 64 - bp;
    const int t = threadIdx.x;
    const int cp = t & 31, j = (t >> 5) & 7, gi = t >> 8;
    const int g = gi ? gb : ga;
    // complex column index cc = ct*32+cp, row stride 2048 complexes (__half2)
    const __half2* inb = (const __half2*)S + (size_t)ct * 32 + cp;

    float2 x[8];
    #pragma unroll
    for (int k = 0; k < 8; ++k)
        x[k] = h2f(inb[(size_t)(64 * g + j + 8 * k) * 2048]);
    {   // stage A
        float2 r[8];
        RADIX8_OUT(x, r)
        #pragma unroll
        for (int i = 0; i < 8; ++i)
            T[gi][8 * j + i][cp] = f2h(r[i]);
    }
    __syncthreads();

    float2 o[8];
    {   // stage B: read rows j+8k, write rows j+8i (same per-thread set)
        #pragma unroll
        for (int k = 0; k < 8; ++k)
            x[k] = h2f(T[gi][j + 8 * k][cp]);
        const float2* twp = (const float2*)tw + j * 8;
        #pragma unroll
        for (int k = 1; k < 8; ++k)
            x[k] = cmulc(x[k], twp[k]);
        RADIX8_OUT(x, o)
        #pragma unroll
        for (int i = 0; i < 8; ++i)
            T[gi][j + 8 * i][cp] = f2h(o[i]);
    }
    __syncthreads();

    // epilogue: k = 64*(j+8i)+g; partner m = (4096-k)&4095 is in this block
    float2* outb = (float2*)Out + (size_t)ct * 32 + cp;
    #pragma unroll
    for (int i = 0; i < 8; ++i) {
        int k = 64 * (j + 8 * i) + g;
        int m = (NF - k) & (NF - 1);
        int gp = m & 63, k1p = m >> 6;
        float2 Zk = o[i];
        float2 Zm = h2f(T[(gp == ga) ? 0 : 1][k1p][cp]);
        float2 E = ((const float2*)ek)[k];
        float2 r;
        r.x = 0.5f * ((Zk.x + Zm.x) * E.x + (Zk.y - Zm.y) * E.y);
        r.y = 0.5f * ((Zk.y + Zm.y) * E.x - (Zk.x - Zm.x) * E.y);
        outb[(size_t)k * 2048] = r;   // cols 2*(ct*32+cp), +1
    }
}

extern "C" void kernel_launch(void* const* d_in, const int* in_sizes, int n_in,
                              void* d_out, int out_size, void* d_ws, size_t ws_size,
                              hipStream_t stream) {
    const float* x = (const float*)d_in[0];
    float* out = (float*)d_out;

    float* tw = (float*)d_ws;           // 4416 float2 = 8832 floats
    float* ek = tw + 8832;              // 4096 float2 = 8192 floats
    __half* B1h = (__half*)(ek + 8192); // 4096*4096 halfs (32 MB) for H
    if (ws_size < (size_t)68096 + (size_t)NF * NF * sizeof(__half)) return;

    setup_tables<<<34, 256, 0, stream>>>(tw, ek);
    // V (fp16) lives in the first 32 MB of d_out; col_fft2 later overwrites
    // d_out with the final fp32 result (V is dead after col_fft1).
    dct_rows<<<NF / 2, 256, 0, stream>>>(x, (__half*)out, tw, ek);
    col_fft1<<<dim3(32, 64), 256, 0, stream>>>((const __half*)out, B1h, tw);
    col_fft2<<<dim3(64, 32), 512, 0, stream>>>(B1h, out, tw, ek);
}